// Round 11
// baseline (1308.642 us; speedup 1.0000x reference)
//
#include <hip/hip_runtime.h>

typedef __attribute__((ext_vector_type(8))) short bf16x8;
typedef __attribute__((ext_vector_type(4))) float f32x4;
typedef unsigned short us;

#define DEVINL __device__ __forceinline__
#define AS1 __attribute__((address_space(1)))
#define AS3 __attribute__((address_space(3)))

constexpr int BB = 4, SS = 4096, DD = 1024, LL = 8192;
// fused-kernel geometry
constexpr int LT_ = 128;            // L rows per block
constexpr int STB = 256;            // S rows per block-tile
constexpr int BK  = 32;             // K per unit
constexpr int NST = SS / STB;       // 16 s-tiles
constexpr int KST = DD / BK;        // 32 k-steps
constexpr int NU  = NST * KST;      // 512 units
constexpr int Z_SH = STB * BK;      // 8192 shorts (16 KiB)
constexpr int SLOT_SH = 2 * Z_SH;   // 16384 shorts (32 KiB): Z + X only
// zgemm geometry
constexpr int ZKST = DD / 64;       // 16

DEVINL unsigned short f2bf(float f){
  union { float f; unsigned u; } a; a.f = f;
  unsigned r = a.u + 0x7fffu + ((a.u >> 16) & 1u);   // RNE
  return (unsigned short)(r >> 16);
}

DEVINL void gll16(const void* src, void* dst){
  __builtin_amdgcn_global_load_lds((const AS1 unsigned int*)src,
                                   (AS3 unsigned int*)dst, 16, 0, 0);
}

__global__ void conv_kernel(const float4* __restrict__ in,
                            ushort4* __restrict__ out, int n4){
  int stride = gridDim.x * blockDim.x;
  for (int i = blockIdx.x*blockDim.x + threadIdx.x; i < n4; i += stride){
    float4 v = in[i];
    ushort4 o;
    o.x = f2bf(v.x); o.y = f2bf(v.y); o.z = f2bf(v.z); o.w = f2bf(v.w);
    out[i] = o;
  }
}

// ---------------- zgemm (round-1 structure, proven, 0 conflicts) ---------
constexpr int ZTILE = 128 * 64;   // shorts per staged tile (BK=64 here)

DEVINL bf16x8 zread_frag(const us* tile, int row, int chunk){
  return *(const AS3 bf16x8*)(tile + row*64 + ((chunk ^ (row & 7)) << 3));
}

DEVINL void stage_tile128(const us* __restrict__ g0, int row0, int d0,
                          us* ldsbase, int wave, int lane){
#pragma unroll
  for (int it = 0; it < 4; ++it){
    int off  = it*4096 + wave*1024 + lane*16;   // byte offset inside tile
    int row  = off >> 7;                        // 128 B per row
    int slot = (off >> 4) & 7;
    int scol = (slot ^ (row & 7)) << 3;
    gll16(g0 + (size_t)(row0 + row) * DD + d0 + scol,
          ldsbase + ((it*4096 + wave*1024) >> 1));
  }
}

__global__ __launch_bounds__(256, 2) void zgemm_kernel(
    const us* __restrict__ X, const us* __restrict__ W,
    const float* __restrict__ Wb, us* __restrict__ Z)
{
  __shared__ __align__(16) us lds[2*ZTILE];   // 32 KiB
  const int bid = blockIdx.x;
  const int tm = bid & 127;
  const int tn = bid >> 7;
  const int tid = threadIdx.x, wave = tid >> 6, lane = tid & 63;
  const int wl = wave >> 1, wn = wave & 1;
  const int g = lane >> 4, cc = lane & 15;

  f32x4 acc[4][4] = {};
#pragma unroll 1
  for (int ks = 0; ks < ZKST; ++ks){
    __syncthreads();
    stage_tile128(X, tm*128, ks*64, lds,         wave, lane);
    stage_tile128(W, tn*128, ks*64, lds + ZTILE, wave, lane);
    __syncthreads();
#pragma unroll
    for (int ksub = 0; ksub < 2; ++ksub){
      bf16x8 af[4], bfr[4];
#pragma unroll
      for (int f = 0; f < 4; ++f) af[f]  = zread_frag(lds,         wl*64 + f*16 + cc, ksub*4 + g);
#pragma unroll
      for (int f = 0; f < 4; ++f) bfr[f] = zread_frag(lds + ZTILE, wn*64 + f*16 + cc, ksub*4 + g);
#pragma unroll
      for (int fm = 0; fm < 4; ++fm)
#pragma unroll
        for (int fn = 0; fn < 4; ++fn)
          acc[fm][fn] = __builtin_amdgcn_mfma_f32_16x16x32_bf16(af[fm], bfr[fn], acc[fm][fn], 0, 0, 0);
    }
  }
#pragma unroll
  for (int fm = 0; fm < 4; ++fm)
#pragma unroll
    for (int fn = 0; fn < 4; ++fn)
#pragma unroll
      for (int r = 0; r < 4; ++r){
        int row = tm*128 + wl*64 + fm*16 + 4*g + r;
        int col = tn*128 + wn*64 + fn*16 + cc;
        float y = acc[fm][fn][r] + Wb[col];
        float e2 = __expf(2.f * y);
        float t = 1.f - 2.f / (e2 + 1.f);
        Z[(size_t)row*DD + col] = f2bf(t);
      }
}

// ---------------- fused: A-in-registers dual-GEMM + exp-weighted reduce ---
// Round-8 pipeline, restructured to kill the LDS wall (measured: 128
// ds_read_b128 + 48 KiB writes/unit/CU ~ 2270 cyc > MFMA 1242):
//  * U,F fragments: DIRECT global->VGPR loads (L1/L2-resident, 64 B
//    segments), double-buffered one unit ahead (ping-pong via unroll-2).
//  * Z,X: gll16 -> LDS, 3 slots x 32 KiB = 96 KiB, swizzled (round 7).
//  * Per unit: 8 ds_reads + 4 gll16 + 8 global loads; 12 vmem ops ->
//    steady s_waitcnt vmcnt(12): forces stage(u+1) + A(u) done, leaves
//    A(u+1)[8] + stage(u+2)[4] in flight.
//  * lgkmcnt(0) BEFORE the barrier: slot-u ds_reads complete before any
//    wave can issue stage(u+3) writes to the same slot (WAR safety).
//  * MFMA2 after the barrier: overlaps stage-issue + next-unit reads.
__global__ __launch_bounds__(512, 2) void fused_kernel(
    const us* __restrict__ U, const us* __restrict__ F,
    const us* __restrict__ Z, const us* __restrict__ X,
    float* __restrict__ pse, float* __restrict__ pac)
{
  __shared__ __align__(16) us lds[3 * SLOT_SH];   // 96 KiB

  const int h = blockIdx.x;            // 256 blocks, 1 per CU
  const int xcd = h & 7, j = h >> 3;   // j in 0..31
  const int lt = xcd * 8 + (j & 7);    // 0..63
  const int b  = j >> 3;               // 0..3

  const int tid = threadIdx.x;
  const int wave = tid >> 6, lane = tid & 63;
  const int wl = wave >> 2, ws = wave & 3;     // 2 L-waves x 4 S-waves
  const int g = lane >> 4, cc = lane & 15;

  const us* Ub = U + (size_t)lt * LT_ * DD;
  const us* Fb = F + (size_t)lt * LT_ * DD;
  const us* Zb = Z + (size_t)b * SS * DD;
  const us* Xb = X + (size_t)b * SS * DD;

  // B staging: LDS chunk c -> row c>>2, slot c&3; fetch logical chunk
  // lg = ((c&3) - (c>>3)) & 3 (bank-conflict swizzle, round-7, verified 0).
  const int lg   = ((tid & 3) - (tid >> 3)) & 3;
  const int offB = (tid >> 2) * DD + lg * 8;

  // read-side swizzled slot (in shorts)
  const int sl8 = ((g + (cc >> 1)) & 3) * 8;
  const int brow = (ws*64 + cc) * BK + sl8;   // + f*16*BK per fragment

  // A-fragment global offsets (shorts): lane (g,cc), frag f reads 16 B at
  // row (wl*64 + f*16 + cc), k-chunk g. 4 g-lanes/row = full 64 B segment.
  int aoffA[4];
#pragma unroll
  for (int f = 0; f < 4; ++f)
    aoffA[f] = (wl*64 + f*16 + cc) * DD + g*8;

  f32x4 sacc[4][4] = {}, gacc[4][4] = {};
  float se_pk = 0.f, ac_pk = 0.f;   // lane-packed running sums

  // stage Z,X k-slices of unit n into slot n%3 (4 gll16 per thread)
  auto stage_unit = [&](int n){
    int nn = (n >= NU) ? n - NU : n;       // tail wrap: harmless re-loads
    us* sb = lds + (n % 3) * SLOT_SH;
    const int k32 = (nn & 31) * BK;
    const size_t stoff = (size_t)(nn >> 5) * STB * DD;
    const us* pZ = Zb + stoff + k32 + offB;
    gll16(pZ,          sb + tid*8);
    gll16(pZ + 128*DD, sb + 4096 + tid*8);
    const us* pX = Xb + stoff + k32 + offB;
    gll16(pX,          sb + Z_SH + tid*8);
    gll16(pX + Z_SH/2*0 + 128*DD, sb + Z_SH + 4096 + tid*8);
  };

  auto epilogue = [&](){
#pragma unroll
    for (int fm = 0; fm < 4; ++fm)
#pragma unroll
      for (int r = 0; r < 4; ++r){
        float ps = 0.f, pg = 0.f;
#pragma unroll
        for (int fn = 0; fn < 4; ++fn){
          float p = __expf(sacc[fm][fn][r]);   // |score| << 88, max-free safe
          ps += p;
          pg += p * gacc[fm][fn][r];
        }
#pragma unroll
        for (int m = 1; m < 16; m <<= 1){
          ps += __shfl_xor(ps, m, 64);
          pg += __shfl_xor(pg, m, 64);
        }
        bool sel = (cc == fm*4 + r);
        se_pk += sel ? ps : 0.f;
        ac_pk += sel ? pg : 0.f;
      }
#pragma unroll
    for (int fm = 0; fm < 4; ++fm)
#pragma unroll
      for (int fn = 0; fn < 4; ++fn){
        sacc[fm][fn] = f32x4{0.f, 0.f, 0.f, 0.f};
        gacc[fm][fn] = f32x4{0.f, 0.f, 0.f, 0.f};
      }
  };

  // one pipeline unit; A-cur consumed, A-next loaded (static ping-pong)
  auto body = [&](int u, bf16x8 (&uaC)[4], bf16x8 (&faC)[4],
                         bf16x8 (&uaN)[4], bf16x8 (&faN)[4]){
    const us* sb = lds + (u % 3) * SLOT_SH;
    bf16x8 z0[4], x1[4];
#pragma unroll
    for (int f = 0; f < 4; ++f)
      z0[f] = *(const AS3 bf16x8*)(sb + brow + f*16*BK);
#pragma unroll
    for (int f = 0; f < 4; ++f)
      x1[f] = *(const AS3 bf16x8*)(sb + Z_SH + brow + f*16*BK);

    // issue A(u+1) global loads (land during this unit's MFMAs)
    int un = u + 1; if (un >= NU) un -= NU;
    const int kn = (un & 31) * BK;
#pragma unroll
    for (int f = 0; f < 4; ++f) uaN[f] = *(const bf16x8*)(Ub + kn + aoffA[f]);
#pragma unroll
    for (int f = 0; f < 4; ++f) faN[f] = *(const bf16x8*)(Fb + kn + aoffA[f]);

    __builtin_amdgcn_s_setprio(1);
#pragma unroll
    for (int fm = 0; fm < 4; ++fm)
#pragma unroll
      for (int fn = 0; fn < 4; ++fn)
        sacc[fm][fn] = __builtin_amdgcn_mfma_f32_16x16x32_bf16(uaC[fm], z0[fn], sacc[fm][fn], 0, 0, 0);
    __builtin_amdgcn_s_setprio(0);

    // all slot-u ds_reads complete before the barrier (WAR vs stage(u+3))
    asm volatile("s_waitcnt lgkmcnt(0)" ::: "memory");
    __builtin_amdgcn_sched_barrier(0);
    asm volatile("s_waitcnt vmcnt(12)" ::: "memory");   // stage(u+1)+A(u) done
    __builtin_amdgcn_s_barrier();
    stage_unit(u + 3);                                   // -> slot u%3, safe

    __builtin_amdgcn_s_setprio(1);
#pragma unroll
    for (int fm = 0; fm < 4; ++fm)
#pragma unroll
      for (int fn = 0; fn < 4; ++fn)
        gacc[fm][fn] = __builtin_amdgcn_mfma_f32_16x16x32_bf16(faC[fm], x1[fn], gacc[fm][fn], 0, 0, 0);
    __builtin_amdgcn_s_setprio(0);

    if ((u & 31) == 31) epilogue();
  };

  // prologue: 3 staged slots + A(0); ensure every wave's stage(0) landed.
  stage_unit(0);
  stage_unit(1);
  stage_unit(2);
  bf16x8 uaA[4], faA[4], uaB[4], faB[4];
#pragma unroll
  for (int f = 0; f < 4; ++f) uaA[f] = *(const bf16x8*)(Ub + aoffA[f]);
#pragma unroll
  for (int f = 0; f < 4; ++f) faA[f] = *(const bf16x8*)(Fb + aoffA[f]);
  asm volatile("s_waitcnt vmcnt(16)" ::: "memory");   // stage(0) done
  __builtin_amdgcn_s_barrier();

#pragma unroll 1
  for (int u = 0; u < NU; u += 2){
    body(u,     uaA, faA, uaB, faB);
    body(u + 1, uaB, faB, uaA, faA);
  }

  // lane (g, cc) holds the (se, ac) sums for row (cc>>2)*16 + 4g + (cc&3)
  {
    int row = (cc >> 2)*16 + 4*g + (cc & 3);
    int l = lt*LT_ + wl*64 + row;
    size_t idx = ((size_t)b*LL + l)*4 + ws;
    pse[idx] = se_pk;
    pac[idx] = ac_pk;
  }
}

__global__ void combine_kernel(const float* __restrict__ pse, const float* __restrict__ pac,
                               const float* __restrict__ fb, float* __restrict__ out)
{
  int i = blockIdx.x*blockDim.x + threadIdx.x;
  if (i >= BB*LL) return;
  int l = i & (LL - 1);
  float s = 0.f, a = 0.f;
#pragma unroll
  for (int k = 0; k < 4; ++k){
    s += pse[(size_t)i*4 + k];
    a += pac[(size_t)i*4 + k];
  }
  out[i] = a / s + fb[l];
}

extern "C" void kernel_launch(void* const* d_in, const int* in_sizes, int n_in,
                              void* d_out, int out_size, void* d_ws, size_t ws_size,
                              hipStream_t stream)
{
  const float* inp = (const float*)d_in[0];   // [B,S,D]
  const float* Ww  = (const float*)d_in[1];   // [D,D]
  const float* Wb  = (const float*)d_in[2];   // [D]
  const float* Uw  = (const float*)d_in[3];   // [L,D]
  const float* Fw  = (const float*)d_in[4];   // [L,D]
  const float* fb  = (const float*)d_in[5];   // [L]
  float* out = (float*)d_out;

  char* ws = (char*)d_ws;
  us* Xbf = (us*)(ws);                            // 32 MiB
  us* Zbf = (us*)(ws + (size_t)32*1024*1024);     // 32 MiB
  us* Ubf = (us*)(ws + (size_t)64*1024*1024);     // 16 MiB
  us* Fbf = (us*)(ws + (size_t)80*1024*1024);     // 16 MiB
  us* Wbf = (us*)(ws + (size_t)96*1024*1024);     //  2 MiB
  float* pse = (float*)(ws + (size_t)98*1024*1024);   // 512 KiB
  float* pac = (float*)(ws + (size_t)99*1024*1024);   // 512 KiB

  conv_kernel<<<2048, 256, 0, stream>>>((const float4*)inp, (ushort4*)Xbf, BB*SS*DD/4);
  conv_kernel<<<256,  256, 0, stream>>>((const float4*)Ww,  (ushort4*)Wbf, DD*DD/4);
  conv_kernel<<<1024, 256, 0, stream>>>((const float4*)Uw,  (ushort4*)Ubf, LL*DD/4);
  conv_kernel<<<1024, 256, 0, stream>>>((const float4*)Fw,  (ushort4*)Fbf, LL*DD/4);

  zgemm_kernel<<<128*8, 256, 0, stream>>>(Xbf, Wbf, Wb, Zbf);
  fused_kernel<<<256, 512, 0, stream>>>(Ubf, Fbf, Zbf, Xbf, pse, pac);
  combine_kernel<<<(BB*LL + 255)/256, 256, 0, stream>>>(pse, pac, fb, out);
}

// Round 12
// 653.931 us; speedup vs baseline: 2.0012x; 2.0012x over previous
//
#include <hip/hip_runtime.h>

typedef __attribute__((ext_vector_type(8))) short bf16x8;
typedef __attribute__((ext_vector_type(4))) float f32x4;
typedef unsigned short us;

#define DEVINL __device__ __forceinline__
#define AS1 __attribute__((address_space(1)))
#define AS3 __attribute__((address_space(3)))

constexpr int BB = 4, SS = 4096, DD = 1024, LL = 8192;
// fused-kernel geometry
constexpr int LT_ = 128;            // L rows per block
constexpr int STB = 256;            // S rows per block-tile
constexpr int BK  = 32;             // K per unit
constexpr int NST = SS / STB;       // 16 s-tiles
constexpr int KST = DD / BK;        // 32 k-steps
constexpr int NU  = NST * KST;      // 512 units
constexpr int U_SH = LT_ * BK;      // 4096 shorts (8 KiB)
constexpr int Z_SH = STB * BK;      // 8192 shorts (16 KiB)
constexpr int SLOT_SH = 2*U_SH + 2*Z_SH;   // 24576 shorts (48 KiB)
// zgemm geometry
constexpr int ZKST = DD / 64;       // 16

DEVINL unsigned short f2bf(float f){
  union { float f; unsigned u; } a; a.f = f;
  unsigned r = a.u + 0x7fffu + ((a.u >> 16) & 1u);   // RNE
  return (unsigned short)(r >> 16);
}

DEVINL void gll16(const void* src, void* dst){
  __builtin_amdgcn_global_load_lds((const AS1 unsigned int*)src,
                                   (AS3 unsigned int*)dst, 16, 0, 0);
}

__global__ void conv_kernel(const float4* __restrict__ in,
                            ushort4* __restrict__ out, int n4){
  int stride = gridDim.x * blockDim.x;
  for (int i = blockIdx.x*blockDim.x + threadIdx.x; i < n4; i += stride){
    float4 v = in[i];
    ushort4 o;
    o.x = f2bf(v.x); o.y = f2bf(v.y); o.z = f2bf(v.z); o.w = f2bf(v.w);
    out[i] = o;
  }
}

// ---------------- zgemm (round-1 structure, proven, 0 conflicts) ---------
constexpr int ZTILE = 128 * 64;   // shorts per staged tile (BK=64 here)

DEVINL bf16x8 zread_frag(const us* tile, int row, int chunk){
  return *(const AS3 bf16x8*)(tile + row*64 + ((chunk ^ (row & 7)) << 3));
}

DEVINL void stage_tile128(const us* __restrict__ g0, int row0, int d0,
                          us* ldsbase, int wave, int lane){
#pragma unroll
  for (int it = 0; it < 4; ++it){
    int off  = it*4096 + wave*1024 + lane*16;   // byte offset inside tile
    int row  = off >> 7;                        // 128 B per row
    int slot = (off >> 4) & 7;
    int scol = (slot ^ (row & 7)) << 3;
    gll16(g0 + (size_t)(row0 + row) * DD + d0 + scol,
          ldsbase + ((it*4096 + wave*1024) >> 1));
  }
}

__global__ __launch_bounds__(256, 2) void zgemm_kernel(
    const us* __restrict__ X, const us* __restrict__ W,
    const float* __restrict__ Wb, us* __restrict__ Z)
{
  __shared__ __align__(16) us lds[2*ZTILE];   // 32 KiB
  const int bid = blockIdx.x;
  const int tm = bid & 127;
  const int tn = bid >> 7;
  const int tid = threadIdx.x, wave = tid >> 6, lane = tid & 63;
  const int wl = wave >> 1, wn = wave & 1;
  const int g = lane >> 4, cc = lane & 15;

  f32x4 acc[4][4] = {};
#pragma unroll 1
  for (int ks = 0; ks < ZKST; ++ks){
    __syncthreads();
    stage_tile128(X, tm*128, ks*64, lds,         wave, lane);
    stage_tile128(W, tn*128, ks*64, lds + ZTILE, wave, lane);
    __syncthreads();
#pragma unroll
    for (int ksub = 0; ksub < 2; ++ksub){
      bf16x8 af[4], bfr[4];
#pragma unroll
      for (int f = 0; f < 4; ++f) af[f]  = zread_frag(lds,         wl*64 + f*16 + cc, ksub*4 + g);
#pragma unroll
      for (int f = 0; f < 4; ++f) bfr[f] = zread_frag(lds + ZTILE, wn*64 + f*16 + cc, ksub*4 + g);
#pragma unroll
      for (int fm = 0; fm < 4; ++fm)
#pragma unroll
        for (int fn = 0; fn < 4; ++fn)
          acc[fm][fn] = __builtin_amdgcn_mfma_f32_16x16x32_bf16(af[fm], bfr[fn], acc[fm][fn], 0, 0, 0);
    }
  }
#pragma unroll
  for (int fm = 0; fm < 4; ++fm)
#pragma unroll
    for (int fn = 0; fn < 4; ++fn)
#pragma unroll
      for (int r = 0; r < 4; ++r){
        int row = tm*128 + wl*64 + fm*16 + 4*g + r;
        int col = tn*128 + wn*64 + fn*16 + cc;
        float y = acc[fm][fn][r] + Wb[col];
        float e2 = __expf(2.f * y);
        float t = 1.f - 2.f / (e2 + 1.f);
        Z[(size_t)row*DD + col] = f2bf(t);
      }
}

// ---------------- fused: de-phased dual-GEMM + exp-weighted reduce -------
// Round-8 pipeline (3 slots, steady vmcnt(6), one s_barrier/unit, proven
// 0-conflict swizzles) + WAVE DE-PHASING: waves with wl=0 run
// {read U,Z -> score MFMA -> read F,X -> G MFMA}; wl=1 waves run the
// mirrored order. SIMD s hosts waves s and s+4 (= opposite wl), so each
// SIMD always has one wave reading LDS while the other issues MFMA ->
// DS pipe and MFMA pipe stay simultaneously busy instead of the
// barrier-locked read-burst/MFMA-burst alternation (round-8 ceiling).
__global__ __launch_bounds__(512, 2) void fused_kernel(
    const us* __restrict__ U, const us* __restrict__ F,
    const us* __restrict__ Z, const us* __restrict__ X,
    float* __restrict__ pse, float* __restrict__ pac)
{
  __shared__ __align__(16) us lds[3 * SLOT_SH];   // 144 KiB

  const int h = blockIdx.x;            // 256 blocks, 1 per CU
  const int xcd = h & 7, j = h >> 3;   // j in 0..31
  const int lt = xcd * 8 + (j & 7);    // 0..63
  const int b  = j >> 3;               // 0..3

  const int tid = threadIdx.x;
  const int wave = tid >> 6, lane = tid & 63;
  const int wl = wave >> 2, ws = wave & 3;     // 2 L-waves x 4 S-waves
  const int g = lane >> 4, cc = lane & 15;

  const us* Ub = U + (size_t)lt * LT_ * DD;
  const us* Fb = F + (size_t)lt * LT_ * DD;
  const us* Zb = Z + (size_t)b * SS * DD;
  const us* Xb = X + (size_t)b * SS * DD;

  // staging: LDS chunk c=tid -> row c>>2, slot c&3; fetch logical chunk
  // lg = ((c&3) - (c>>3)) & 3 (bank-conflict swizzle, verified 0).
  const int lg   = ((tid & 3) - (tid >> 3)) & 3;
  const int offA = (tid >> 2) * DD + lg * 8;

  // read-side swizzled slot (in shorts)
  const int sl8 = ((g + (cc >> 1)) & 3) * 8;

  // per-wave LDS row bases for fragment reads
  const int arow = (wl*64 + cc) * BK + sl8;   // + f*16*BK per fragment
  const int brow = (ws*64 + cc) * BK + sl8;

  f32x4 sacc[4][4] = {}, gacc[4][4] = {};
  float se_pk = 0.f, ac_pk = 0.f;   // lane-packed running sums

  auto stage_unit = [&](int n){
    int nn = (n >= NU) ? n - NU : n;       // tail wrap: harmless re-loads
    us* sb = lds + (n % 3) * SLOT_SH;
    const int k32 = (nn & 31) * BK;
    const size_t stoff = (size_t)(nn >> 5) * STB * DD;
    gll16(Ub + k32 + offA, sb + tid*8);
    gll16(Fb + k32 + offA, sb + U_SH + tid*8);
    const us* pZ = Zb + stoff + k32 + offA;
    gll16(pZ,          sb + 2*U_SH + tid*8);
    gll16(pZ + 128*DD, sb + 2*U_SH + 4096 + tid*8);
    const us* pX = Xb + stoff + k32 + offA;
    gll16(pX,          sb + 2*U_SH + Z_SH + tid*8);
    gll16(pX + 128*DD, sb + 2*U_SH + Z_SH + 4096 + tid*8);
  };

  auto do_score = [&](const us* sb){
    const us* tU = sb;
    const us* tZ = sb + 2*U_SH;
    bf16x8 a0[4], b0[4];
#pragma unroll
    for (int f = 0; f < 4; ++f)
      a0[f] = *(const AS3 bf16x8*)(tU + arow + f*16*BK);
#pragma unroll
    for (int f = 0; f < 4; ++f)
      b0[f] = *(const AS3 bf16x8*)(tZ + brow + f*16*BK);
    __builtin_amdgcn_s_setprio(1);
#pragma unroll
    for (int fm = 0; fm < 4; ++fm)
#pragma unroll
      for (int fn = 0; fn < 4; ++fn)
        sacc[fm][fn] = __builtin_amdgcn_mfma_f32_16x16x32_bf16(a0[fm], b0[fn], sacc[fm][fn], 0, 0, 0);
    __builtin_amdgcn_s_setprio(0);
  };

  auto do_g = [&](const us* sb){
    const us* tF = sb + U_SH;
    const us* tX = sb + 2*U_SH + Z_SH;
    bf16x8 a1[4], b1[4];
#pragma unroll
    for (int f = 0; f < 4; ++f)
      a1[f] = *(const AS3 bf16x8*)(tF + arow + f*16*BK);
#pragma unroll
    for (int f = 0; f < 4; ++f)
      b1[f] = *(const AS3 bf16x8*)(tX + brow + f*16*BK);
    __builtin_amdgcn_s_setprio(1);
#pragma unroll
    for (int fm = 0; fm < 4; ++fm)
#pragma unroll
      for (int fn = 0; fn < 4; ++fn)
        gacc[fm][fn] = __builtin_amdgcn_mfma_f32_16x16x32_bf16(a1[fm], b1[fn], gacc[fm][fn], 0, 0, 0);
    __builtin_amdgcn_s_setprio(0);
  };

  auto epilogue = [&](){
#pragma unroll
    for (int fm = 0; fm < 4; ++fm)
#pragma unroll
      for (int r = 0; r < 4; ++r){
        float ps = 0.f, pg = 0.f;
#pragma unroll
        for (int fn = 0; fn < 4; ++fn){
          float p = __expf(sacc[fm][fn][r]);   // |score| << 88, max-free safe
          ps += p;
          pg += p * gacc[fm][fn][r];
        }
#pragma unroll
        for (int m = 1; m < 16; m <<= 1){
          ps += __shfl_xor(ps, m, 64);
          pg += __shfl_xor(pg, m, 64);
        }
        bool sel = (cc == fm*4 + r);
        se_pk += sel ? ps : 0.f;
        ac_pk += sel ? pg : 0.f;
      }
#pragma unroll
    for (int fm = 0; fm < 4; ++fm)
#pragma unroll
      for (int fn = 0; fn < 4; ++fn){
        sacc[fm][fn] = f32x4{0.f, 0.f, 0.f, 0.f};
        gacc[fm][fn] = f32x4{0.f, 0.f, 0.f, 0.f};
      }
  };

  stage_unit(0);
  stage_unit(1);
  stage_unit(2);
  asm volatile("s_waitcnt vmcnt(12)" ::: "memory");   // stage(0) landed
  __builtin_amdgcn_s_barrier();                       // ...for all waves

#pragma unroll 1
  for (int u = 0; u < NU; ++u){
    const us* sb = lds + (u % 3) * SLOT_SH;

    // De-phased dual GEMM: wl=0 waves score-first, wl=1 waves G-first.
    if (wl == 0){
      do_score(sb);
      __builtin_amdgcn_sched_barrier(0);
      do_g(sb);
    } else {
      do_g(sb);
      __builtin_amdgcn_sched_barrier(0);
      do_score(sb);
    }

    // all slot-u ds_reads complete before the barrier (WAR vs stage(u+3));
    // stage(u+1) landed for every wave; stage(u+2)'s 6 stay in flight.
    asm volatile("s_waitcnt lgkmcnt(0)" ::: "memory");
    __builtin_amdgcn_sched_barrier(0);
    asm volatile("s_waitcnt vmcnt(6)" ::: "memory");
    __builtin_amdgcn_s_barrier();
    stage_unit(u + 3);                 // -> slot u%3, safe post-barrier

    if ((u & 31) == 31) epilogue();
  }

  // lane (g, cc) holds the (se, ac) sums for row (cc>>2)*16 + 4g + (cc&3)
  {
    int row = (cc >> 2)*16 + 4*g + (cc & 3);
    int l = lt*LT_ + wl*64 + row;
    size_t idx = ((size_t)b*LL + l)*4 + ws;
    pse[idx] = se_pk;
    pac[idx] = ac_pk;
  }
}

__global__ void combine_kernel(const float* __restrict__ pse, const float* __restrict__ pac,
                               const float* __restrict__ fb, float* __restrict__ out)
{
  int i = blockIdx.x*blockDim.x + threadIdx.x;
  if (i >= BB*LL) return;
  int l = i & (LL - 1);
  float s = 0.f, a = 0.f;
#pragma unroll
  for (int k = 0; k < 4; ++k){
    s += pse[(size_t)i*4 + k];
    a += pac[(size_t)i*4 + k];
  }
  out[i] = a / s + fb[l];
}

extern "C" void kernel_launch(void* const* d_in, const int* in_sizes, int n_in,
                              void* d_out, int out_size, void* d_ws, size_t ws_size,
                              hipStream_t stream)
{
  const float* inp = (const float*)d_in[0];   // [B,S,D]
  const float* Ww  = (const float*)d_in[1];   // [D,D]
  const float* Wb  = (const float*)d_in[2];   // [D]
  const float* Uw  = (const float*)d_in[3];   // [L,D]
  const float* Fw  = (const float*)d_in[4];   // [L,D]
  const float* fb  = (const float*)d_in[5];   // [L]
  float* out = (float*)d_out;

  char* ws = (char*)d_ws;
  us* Xbf = (us*)(ws);                            // 32 MiB
  us* Zbf = (us*)(ws + (size_t)32*1024*1024);     // 32 MiB
  us* Ubf = (us*)(ws + (size_t)64*1024*1024);     // 16 MiB
  us* Fbf = (us*)(ws + (size_t)80*1024*1024);     // 16 MiB
  us* Wbf = (us*)(ws + (size_t)96*1024*1024);     //  2 MiB
  float* pse = (float*)(ws + (size_t)98*1024*1024);   // 512 KiB
  float* pac = (float*)(ws + (size_t)99*1024*1024);   // 512 KiB

  conv_kernel<<<2048, 256, 0, stream>>>((const float4*)inp, (ushort4*)Xbf, BB*SS*DD/4);
  conv_kernel<<<256,  256, 0, stream>>>((const float4*)Ww,  (ushort4*)Wbf, DD*DD/4);
  conv_kernel<<<1024, 256, 0, stream>>>((const float4*)Uw,  (ushort4*)Ubf, LL*DD/4);
  conv_kernel<<<1024, 256, 0, stream>>>((const float4*)Fw,  (ushort4*)Fbf, LL*DD/4);

  zgemm_kernel<<<128*8, 256, 0, stream>>>(Xbf, Wbf, Wb, Zbf);
  fused_kernel<<<256, 512, 0, stream>>>(Ubf, Fbf, Zbf, Xbf, pse, pac);
  combine_kernel<<<(BB*LL + 255)/256, 256, 0, stream>>>(pse, pac, fb, out);
}